// Round 6
// baseline (3838.982 us; speedup 1.0000x reference)
//
#include <hip/hip_runtime.h>
#include <math.h>

// Problem constants (fixed by setup_inputs)
#define NN   256   // nodes
#define HH   450   // hidden
#define LATD 56    // latent
#define VV   780   // vocab
#define LL   511   // path length (2N-1)
#define GSEQ 32    // persistent blocks
#define TSEQ 512   // threads per persistent block
#define KMAX 15    // max rows per block (450 = 15+15+14*30)
#define AST  16    // accumulator row stride (pad 15 -> 16)
#define SLOTJ 520  // ull stride per slot (4160 B: skewed off 4 KB to spread channels)

__device__ __forceinline__ float wred_sum(float v) {
    for (int off = 32; off; off >>= 1) v += __shfl_down(v, off, 64);
    return v;
}

// ---- agent-scope relaxed atomics (coherent at device level) ----
__device__ __forceinline__ void aadd(float* p, float v) {
    (void)__hip_atomic_fetch_add(p, v, __ATOMIC_RELAXED, __HIP_MEMORY_SCOPE_AGENT);
}
__device__ __forceinline__ unsigned long long aload64(const unsigned long long* p) {
    return __hip_atomic_load(p, __ATOMIC_RELAXED, __HIP_MEMORY_SCOPE_AGENT);
}
__device__ __forceinline__ void astore64(unsigned long long* p, unsigned long long v) {
    __hip_atomic_store(p, v, __ATOMIC_RELAXED, __HIP_MEMORY_SCOPE_AGENT);
}
__device__ __forceinline__ unsigned long long packft(float f, unsigned tag) {
    union { float f; unsigned u; } c; c.f = f;
    return (unsigned long long)c.u | ((unsigned long long)tag << 32);
}
__device__ __forceinline__ float unpackf(unsigned long long v) {
    union { unsigned u; float f; } c; c.u = (unsigned)v;
    return c.f;
}

// ---- find vocab id of each node's one-hot feature ----
__global__ void k_vid(const float* __restrict__ nf, int* __restrict__ vid) {
    const int u = blockIdx.x;
    for (int v = threadIdx.x; v < VV; v += blockDim.x)
        if (nf[(size_t)u * VV + v] > 0.5f) vid[u] = v;
}

// ---- per-node constants: cz, r1, sigma(r1), ch, and Ud . relu(d12) scalar ----
__global__ __launch_bounds__(512) void k_consts(
    const int* __restrict__ vid, const float* __restrict__ latent,
    const float* __restrict__ Wz, const float* __restrict__ Wzb,
    const float* __restrict__ Wr, const float* __restrict__ Wrb,
    const float* __restrict__ Wh, const float* __restrict__ Whb,
    const float* __restrict__ Wd12, const float* __restrict__ Wd12b,
    const float* __restrict__ Ud,
    float* __restrict__ cz, float* __restrict__ r1s, float* __restrict__ sig0,
    float* __restrict__ ch, float* __restrict__ dotd12)
{
    const int u = blockIdx.x, tid = threadIdx.x;
    const int v = vid[u];
    __shared__ float red[8];
    float p = 0.f;
    if (tid < HH) {
        const int i = tid, o = u * HH + i;
        cz[o] = Wz[(size_t)i * (VV + HH) + v] + Wzb[i];
        const float r1 = Wr[(size_t)i * VV + v] + Wrb[i];
        r1s[o] = r1;
        sig0[o] = 1.f / (1.f + expf(-r1));
        ch[o] = Wh[(size_t)i * (VV + HH) + v] + Whb[i];
        float d = Wd12[(size_t)i * (VV + LATD) + v] + Wd12b[i];
        for (int k = 0; k < LATD; ++k)
            d += Wd12[(size_t)i * (VV + LATD) + VV + k] * latent[k];
        p = Ud[i] * fmaxf(d, 0.f);
    }
    p = wred_sum(p);
    if ((tid & 63) == 0) red[tid >> 6] = p;
    __syncthreads();
    if (tid == 0) {
        float s = 0.f;
        for (int w = 0; w < 8; ++w) s += red[w];
        dotd12[u] = s;
    }
}

// ---- WhSig0[u] = Wh_H @ sigma(r1[u]) ----
__global__ __launch_bounds__(512) void k_whsig0(
    const float* __restrict__ Wh, const float* __restrict__ sig0, float* __restrict__ out)
{
    const int u = blockIdx.x, tid = threadIdx.x, wave = tid >> 6, lane = tid & 63;
    __shared__ float sg[HH];
    if (tid < HH) sg[tid] = sig0[u * HH + tid];
    __syncthreads();
    for (int r = wave; r < HH; r += 8) {
        float acc = 0.f;
        for (int k = lane; k < HH; k += 64)
            acc += Wh[(size_t)r * (VV + HH) + VV + k] * sg[k];
        acc = wred_sum(acc);
        if (lane == 0) out[u * HH + r] = acc;
    }
}

// ---- per-step exclusion index + precomputed neighbor-count coefficient ----
__global__ void k_excl(const int* __restrict__ node_ids, const int* __restrict__ next_ids,
                       int* __restrict__ excl, float* __restrict__ ccpre)
{
    const int t = blockIdx.x;
    __shared__ int ex, cnt;
    if (threadIdx.x == 0) { ex = -1; cnt = 0; }
    __syncthreads();
    const int a = node_ids[t], b = next_ids[t];
    for (int tp = threadIdx.x; tp <= t; tp += blockDim.x) {
        if (tp < t && node_ids[tp] == b && next_ids[tp] == a) ex = tp;
        if (tp >= 1 && node_ids[tp] == a) atomicAdd(&cnt, 1);
    }
    __syncthreads();
    if (threadIdx.x == 0) {
        excl[t] = ex;
        ccpre[t] = 256.f - (float)cnt + (ex >= 0 ? 1.f : 0.f);
    }
}

// ---- copy stops/real_labels into d_out; zero the pred_stop region ----
__global__ void k_copy(const int* __restrict__ stops, const int* __restrict__ reall,
                       float* __restrict__ out)
{
    const int i = blockIdx.x * blockDim.x + threadIdx.x;
    if (i < LL) { out[i] = (float)stops[i]; out[LL + i] = 0.f; }
    if (i < NN) out[2 * LL + i] = (float)reall[i];
}

// ---- sequential scan: ZERO barriers, pure tagged dataflow ----
// Block b owns rows R_b. Column-partitioned first layer: each thread r<450
// computes 3 partials from register weight columns and stores them TAGGED
// (value,step) as one 8B word into this block's slot. Consumers poll the
// tagged words directly (detection==gather), sum 32 slots in fixed order.
// Skew is bounded: parity-p slots for step t+2 can't be written until every
// block consumed step t (produce/consume ordering), so no overwrite races.
__global__ __launch_bounds__(TSEQ) void k_seq(
    const int* __restrict__ node_ids, const int* __restrict__ excl,
    const float* __restrict__ ccpre,
    const float* __restrict__ Ur, const float* __restrict__ Wz,
    const float* __restrict__ Wh, const float* __restrict__ Wd3,
    const float* __restrict__ Wd3b, const float* __restrict__ Ud,
    const float* __restrict__ Udb,
    const float* __restrict__ cz, const float* __restrict__ r1s,
    const float* __restrict__ ch, const float* __restrict__ WhSig0,
    const float* __restrict__ dotd12,
    float* __restrict__ SmL, float* __restrict__ WzSmL,
    float* __restrict__ Wd3SmL, float* __restrict__ WhRsL,
    float* __restrict__ NewHL, float* __restrict__ WzML, float* __restrict__ WhSvL,
    unsigned long long* __restrict__ slotUr, unsigned long long* __restrict__ slotWz,
    unsigned long long* __restrict__ slotWd3,
    float* __restrict__ pred_out)
{
    const int tid = threadIdx.x, bid = blockIdx.x;
    const int wave = tid >> 6, lane = tid & 63;
    const int kcnt = 14 + (bid < 2 ? 1 : 0);
    const int kbeg = 14 * bid + (bid < 2 ? bid : 2);

    float* mySm   = SmL    + (size_t)bid * NN * AST;
    float* myWzSm = WzSmL  + (size_t)bid * NN * AST;
    float* myWd3S = Wd3SmL + (size_t)bid * NN * AST;
    float* myWhRs = WhRsL  + (size_t)bid * NN * AST;
    float* myNewH = NewHL  + (size_t)bid * LL * AST;
    float* myWzM  = WzML   + (size_t)bid * LL * AST;
    float* myWhSv = WhSvL  + (size_t)bid * LL * AST;

    __shared__ float nh_s[KMAX];
    __shared__ float sig_full[512];
    __shared__ float wzsum[KMAX];
    __shared__ float wd3sum[KMAX];

    // Column slices of Ur / Wz_H / Wd3: thread r holds row r's R_b columns
    float ur_c[KMAX], wz_c[KMAX], wd3_c[KMAX];
    for (int j = 0; j < KMAX; ++j) {
        const bool v = (tid < HH) && (j < kcnt);
        ur_c[j]  = v ? Ur[(size_t)tid * HH + kbeg + j] : 0.f;
        wz_c[j]  = v ? Wz[(size_t)tid * (VV + HH) + VV + kbeg + j] : 0.f;
        wd3_c[j] = v ? Wd3[(size_t)tid * HH + kbeg + j] : 0.f;
    }
    // Row slice of Wh_H (second matvec, row-partitioned fold)
    float wh_r[2][8];
    for (int it = 0; it < 2; ++it) {
        const int j = wave + 8 * it;
        const bool vj = j < kcnt;
        const int i = vj ? (kbeg + j) : 0;
        for (int e = 0; e < 8; ++e) {
            const int c = lane + 64 * e;
            wh_r[it][e] = (vj && c < HH) ? Wh[(size_t)i * (VV + HH) + VV + c] : 0.f;
        }
    }
    if (tid >= HH) sig_full[tid] = 0.f;   // zero pad once
    __syncthreads();

    for (int t = 1; t <= LL; ++t) {
        const int ap  = node_ids[t - 1];
        const int idx = excl[t - 1];
        // ---- A: new_h(t-1) own rows (all-local reads) ----
        float nh = 0.f;
        if (tid < kcnt) {
            const int r = kbeg + tid;
            const int o = ap * HH + r;
            const int oa = ap * AST + tid;
            float zarg = myWzSm[oa] + cz[o];
            float whv  = myWhRs[oa] + ch[o];
            float sv   = mySm[oa];
            if (idx >= 0) {
                const int oe = idx * AST + tid;
                zarg -= myWzM[oe]; whv -= myWhSv[oe]; sv -= myNewH[oe];
            }
            whv += ccpre[t - 1] * WhSig0[o];
            const float z = 1.f / (1.f + expf(-zarg));
            nh = (1.f - z) * sv + z * tanhf(whv);
            nh_s[tid] = nh;
            myNewH[(t - 1) * AST + tid] = nh;
        }
        if (tid >= 480 && tid < 480 + KMAX) wzsum[tid - 480] = 0.f;
        if (tid >= 496 && tid < 496 + KMAX) wd3sum[tid - 496] = 0.f;
        // pred_stop(t-1): own rows live in wave 0; fire-and-forget
        if (wave == 0) {
            float ps = 0.f;
            if (tid < kcnt) {
                const int r = kbeg + tid;
                ps = Ud[HH + r] * fmaxf(myWd3S[ap * AST + tid] + Wd3b[r], 0.f);
            }
            ps = wred_sum(ps);
            if (lane == 0) {
                if (bid == 0) ps += dotd12[ap] + Udb[0];
                aadd(&pred_out[t - 1], ps);
            }
        }
        if (t == LL) break;   // last step: no ingestion (is_last masked)
        const int a = node_ids[t];
        __syncthreads();       // nh_s visible; LDS sums zeroed

        const int p = t & 1;
        const unsigned tag = (unsigned)t;
        // ---- produce: tagged partial publish (no drain, no flag) ----
        if (tid < HH) {
            float au = 0.f, az = 0.f, ad = 0.f;
            for (int j = 0; j < kcnt; ++j) {
                const float m = nh_s[j];
                au += ur_c[j]  * m;
                az += wz_c[j]  * m;
                ad += wd3_c[j] * m;
            }
            const size_t so = (size_t)(p * GSEQ + bid) * SLOTJ + tid;
            astore64(&slotUr[so],  packft(au, tag));
            astore64(&slotWz[so],  packft(az, tag));
            astore64(&slotWd3[so], packft(ad, tag));
        }
        if (tid < kcnt) mySm[a * AST + tid] += nh;   // local fold

        // ---- consume: tagged poll-gather (detection == gather) ----
        if (tid < HH) {
            // Ur row tid: sum 32 tagged partials
            unsigned long long vv[GSEQ];
            const unsigned long long* base = slotUr + (size_t)p * GSEQ * SLOTJ + tid;
            #pragma unroll
            for (int j = 0; j < GSEQ; ++j) vv[j] = aload64(base + (size_t)j * SLOTJ);
            for (;;) {
                bool ok = true;
                #pragma unroll
                for (int j = 0; j < GSEQ; ++j)
                    if ((unsigned)(vv[j] >> 32) != tag) {
                        ok = false;
                        vv[j] = aload64(base + (size_t)j * SLOTJ);
                    }
                if (ok) break;
            }
            float urm = 0.f;
            #pragma unroll
            for (int j = 0; j < GSEQ; ++j) urm += unpackf(vv[j]);
            sig_full[tid] = 1.f / (1.f + expf(-(urm + r1s[a * HH + tid])));
        } else {
            // threads 450..511: gather own Wz/Wd3 rows (16 slots each, 2/row)
            const int q = tid - HH;           // 0..61
            if (q < 60) {
                const bool isWz = q < 30;
                const int qq = isWz ? q : q - 30;
                const int row = qq >> 1;      // local row 0..14
                if (row < kcnt) {
                    const int sbase = (qq & 1) * 16;
                    const unsigned long long* basem =
                        (isWz ? slotWz : slotWd3) + (size_t)p * GSEQ * SLOTJ + (kbeg + row);
                    unsigned long long vv[16];
                    #pragma unroll
                    for (int s = 0; s < 16; ++s)
                        vv[s] = aload64(basem + (size_t)(sbase + s) * SLOTJ);
                    for (;;) {
                        bool ok = true;
                        #pragma unroll
                        for (int s = 0; s < 16; ++s)
                            if ((unsigned)(vv[s] >> 32) != tag) {
                                ok = false;
                                vv[s] = aload64(basem + (size_t)(sbase + s) * SLOTJ);
                            }
                        if (ok) break;
                    }
                    float sum = 0.f;
                    #pragma unroll
                    for (int s = 0; s < 16; ++s) sum += unpackf(vv[s]);
                    atomicAdd(isWz ? &wzsum[row] : &wd3sum[row], sum);
                }
            }
        }
        __syncthreads();   // sig_full + wzsum/wd3sum complete

        // ---- folds: Wz/Wd3 own rows; Wh own rows x full sigma ----
        if (tid < kcnt) {
            const float wzm = wzsum[tid];
            myWzM[(t - 1) * AST + tid] = wzm;
            myWzSm[a * AST + tid] += wzm;
            myWd3S[a * AST + tid] += wd3sum[tid];
        }
        for (int it = 0; it < 2; ++it) {
            const int j = wave + 8 * it;
            float acc = 0.f;
            #pragma unroll
            for (int e = 0; e < 8; ++e) acc += wh_r[it][e] * sig_full[lane + 64 * e];
            acc = wred_sum(acc);
            if (lane == 0 && j < kcnt) {
                myWhSv[(t - 1) * AST + j] = acc;
                myWhRs[a * AST + j] += acc;
            }
        }
        __syncthreads();   // folds complete before next A reads them
    }
}

// ---- labels: root (q=0, outer relu, no softmax) + 255 label steps (softmax) ----
__global__ __launch_bounds__(512) void k_label(
    const float* __restrict__ latent, const int* __restrict__ lsteps,
    const float* __restrict__ NewHL,
    const float* __restrict__ Wl, const float* __restrict__ Wlb,
    const float* __restrict__ Ul, const float* __restrict__ Ulb,
    float* __restrict__ out)
{
    const int q = blockIdx.x, tid = threadIdx.x, wave = tid >> 6, lane = tid & 63;
    __shared__ float inp[LATD + HH];
    __shared__ float t2[HH];
    __shared__ float lg[VV];
    __shared__ float red[8];
    if (tid < LATD) inp[tid] = latent[tid];
    if (q == 0) {
        if (tid < HH) inp[LATD + tid] = 0.f;
    } else {
        const int t = lsteps[q - 1];
        if (tid < HH) {
            const int b = (tid < 30) ? (tid / 15) : (2 + (tid - 30) / 14);
            const int j = (tid < 30) ? (tid % 15) : ((tid - 30) % 14);
            inp[LATD + tid] = NewHL[((size_t)b * LL + t) * AST + j];
        }
    }
    __syncthreads();
    for (int r = wave; r < HH; r += 8) {
        float acc = 0.f;
        for (int k = lane; k < LATD + HH; k += 64)
            acc += Wl[(size_t)r * (LATD + HH) + k] * inp[k];
        acc = wred_sum(acc);
        if (lane == 0) {
            const float v = acc + Wlb[r];
            t2[r] = (q == 0) ? v : fmaxf(v, 0.f);   // root: no inner relu
        }
    }
    __syncthreads();
    for (int r = wave; r < VV; r += 8) {
        float acc = 0.f;
        for (int k = lane; k < HH; k += 64) acc += Ul[(size_t)r * HH + k] * t2[k];
        acc = wred_sum(acc);
        if (lane == 0) lg[r] = acc + Ulb[r];
    }
    __syncthreads();
    float* outrow = out + 2 * LL + NN + (size_t)q * VV;
    if (q == 0) {   // root: relu, no softmax
        for (int i = tid; i < VV; i += 512) outrow[i] = fmaxf(lg[i], 0.f);
        return;
    }
    float mx = -1e30f;
    for (int i = tid; i < VV; i += 512) mx = fmaxf(mx, lg[i]);
    for (int off = 32; off; off >>= 1) mx = fmaxf(mx, __shfl_down(mx, off, 64));
    if (lane == 0) red[wave] = mx;
    __syncthreads();
    if (tid == 0) {
        float m = red[0];
        for (int w = 1; w < 8; ++w) m = fmaxf(m, red[w]);
        red[0] = m;
    }
    __syncthreads();
    const float M = red[0];
    float sum = 0.f;
    for (int i = tid; i < VV; i += 512) { const float e = expf(lg[i] - M); lg[i] = e; sum += e; }
    __syncthreads();
    sum = wred_sum(sum);
    if (lane == 0) red[wave] = sum;
    __syncthreads();
    if (tid == 0) {
        float s = 0.f;
        for (int w = 0; w < 8; ++w) s += red[w];
        red[0] = s;
    }
    __syncthreads();
    const float S = red[0];
    for (int i = tid; i < VV; i += 512) outrow[i] = lg[i] / S;
}

extern "C" void kernel_launch(void* const* d_in, const int* in_sizes, int n_in,
                              void* d_out, int out_size, void* d_ws, size_t ws_size,
                              hipStream_t stream)
{
    const float* latent = (const float*)d_in[0];
    const float* nodef  = (const float*)d_in[1];
    const int* node_ids = (const int*)d_in[2];
    const int* next_ids = (const int*)d_in[3];
    const int* stops    = (const int*)d_in[4];
    const int* lsteps   = (const int*)d_in[5];
    const int* reall    = (const int*)d_in[6];
    const float* Wz   = (const float*)d_in[7];
    const float* Wzb  = (const float*)d_in[8];
    const float* Urw  = (const float*)d_in[9];
    const float* Wr   = (const float*)d_in[10];
    const float* Wrb  = (const float*)d_in[11];
    const float* Wh   = (const float*)d_in[12];
    const float* Whb  = (const float*)d_in[13];
    const float* Wd12 = (const float*)d_in[14];
    const float* Wd12b= (const float*)d_in[15];
    const float* Wd3  = (const float*)d_in[16];
    const float* Wd3b = (const float*)d_in[17];
    const float* Ud   = (const float*)d_in[18];
    const float* Udb  = (const float*)d_in[19];
    const float* Wl   = (const float*)d_in[20];
    const float* Wlb  = (const float*)d_in[21];
    const float* Ul   = (const float*)d_in[22];
    const float* Ulb  = (const float*)d_in[23];
    (void)in_sizes; (void)n_in; (void)out_size; (void)ws_size;
    float* out = (float*)d_out;
    float* W = (float*)d_ws;

    size_t o = 0;
    float* SmL    = W + o; o += (size_t)GSEQ * NN * AST;
    float* WzSmL  = W + o; o += (size_t)GSEQ * NN * AST;
    float* Wd3SmL = W + o; o += (size_t)GSEQ * NN * AST;
    float* WhRsL  = W + o; o += (size_t)GSEQ * NN * AST;
    const size_t zero_floats = o;           // everything above must start at 0
    int*   vid    = (int*)(W + o); o += NN;
    int*   excl   = (int*)(W + o); o += LL + 1;
    float* ccpre  = W + o; o += LL + 1;
    float* cz     = W + o; o += NN * HH;
    float* r1s    = W + o; o += NN * HH;
    float* sig0   = W + o; o += NN * HH;
    float* ch     = W + o; o += NN * HH;
    float* WhSig0 = W + o; o += NN * HH;
    float* dotd12 = W + o; o += NN;
    float* NewHL  = W + o; o += (size_t)GSEQ * LL * AST;
    float* WzML   = W + o; o += (size_t)GSEQ * LL * AST;
    float* WhSvL  = W + o; o += (size_t)GSEQ * LL * AST;
    o = (o + 1) & ~(size_t)1;               // 8B align for ull slots
    unsigned long long* slotUr  = (unsigned long long*)(W + o); o += 2ull * 2 * GSEQ * SLOTJ;
    unsigned long long* slotWz  = (unsigned long long*)(W + o); o += 2ull * 2 * GSEQ * SLOTJ;
    unsigned long long* slotWd3 = (unsigned long long*)(W + o); o += 2ull * 2 * GSEQ * SLOTJ;
    // slots need no init: poison tag 0xAAAAAAAA never equals a step tag

    hipMemsetAsync(W, 0, zero_floats * sizeof(float), stream);
    k_vid   <<<NN, 256, 0, stream>>>(nodef, vid);
    k_consts<<<NN, 512, 0, stream>>>(vid, latent, Wz, Wzb, Wr, Wrb, Wh, Whb,
                                     Wd12, Wd12b, Ud, cz, r1s, sig0, ch, dotd12);
    k_whsig0<<<NN, 512, 0, stream>>>(Wh, sig0, WhSig0);
    k_excl  <<<LL, 256, 0, stream>>>(node_ids, next_ids, excl, ccpre);
    k_copy  <<<2, 256, 0, stream>>>(stops, reall, out);
    k_seq   <<<GSEQ, TSEQ, 0, stream>>>(node_ids, excl, ccpre, Urw, Wz, Wh, Wd3, Wd3b,
                                        Ud, Udb, cz, r1s, ch, WhSig0, dotd12,
                                        SmL, WzSmL, Wd3SmL, WhRsL,
                                        NewHL, WzML, WhSvL,
                                        slotUr, slotWz, slotWd3,
                                        out + LL);
    k_label <<<NN, 512, 0, stream>>>(latent, lsteps, NewHL, Wl, Wlb, Ul, Ulb, out);
}

// Round 8
// 3411.131 us; speedup vs baseline: 1.1254x; 1.1254x over previous
//
#include <hip/hip_runtime.h>
#include <math.h>

// Problem constants (fixed by setup_inputs)
#define NN   256   // nodes
#define HH   450   // hidden
#define LATD 56    // latent
#define VV   780   // vocab
#define LL   511   // path length (2N-1)
#define GSEQ 32    // persistent blocks
#define TSEQ 512   // threads per persistent block
#define KMAX 15    // max rows per block (450 = 15+15+14*30)
#define AST  16    // accumulator row stride (pad 15 -> 16)

#define FIXS 16777216.0f          // 2^24 fixed-point scale
#define CNT1 (1ll << 45)          // per-producer count increment
#define CHALF (1ll << 44)         // rounding bias for count extraction

__device__ __forceinline__ float wred_sum(float v) {
    for (int off = 32; off; off >>= 1) v += __shfl_down(v, off, 64);
    return v;
}

// ---- agent-scope relaxed atomics (coherent at device level) ----
__device__ __forceinline__ void aaddf(float* p, float v) {
    (void)__hip_atomic_fetch_add(p, v, __ATOMIC_RELAXED, __HIP_MEMORY_SCOPE_AGENT);
}
__device__ __forceinline__ void aadd64(unsigned long long* p, unsigned long long v) {
    (void)__hip_atomic_fetch_add(p, v, __ATOMIC_RELAXED, __HIP_MEMORY_SCOPE_AGENT);
}
__device__ __forceinline__ long long aload64(const unsigned long long* p) {
    return (long long)__hip_atomic_load(p, __ATOMIC_RELAXED, __HIP_MEMORY_SCOPE_AGENT);
}
__device__ __forceinline__ unsigned long long packc(float x) {
    return (unsigned long long)(CNT1 + (long long)llrintf(x * FIXS));
}

// ---- find vocab id of each node's one-hot feature ----
__global__ void k_vid(const float* __restrict__ nf, int* __restrict__ vid) {
    const int u = blockIdx.x;
    for (int v = threadIdx.x; v < VV; v += blockDim.x)
        if (nf[(size_t)u * VV + v] > 0.5f) vid[u] = v;
}

// ---- per-node constants: cz, r1, sigma(r1), ch, and Ud . relu(d12) scalar ----
__global__ __launch_bounds__(512) void k_consts(
    const int* __restrict__ vid, const float* __restrict__ latent,
    const float* __restrict__ Wz, const float* __restrict__ Wzb,
    const float* __restrict__ Wr, const float* __restrict__ Wrb,
    const float* __restrict__ Wh, const float* __restrict__ Whb,
    const float* __restrict__ Wd12, const float* __restrict__ Wd12b,
    const float* __restrict__ Ud,
    float* __restrict__ cz, float* __restrict__ r1s, float* __restrict__ sig0,
    float* __restrict__ ch, float* __restrict__ dotd12)
{
    const int u = blockIdx.x, tid = threadIdx.x;
    const int v = vid[u];
    __shared__ float red[8];
    float p = 0.f;
    if (tid < HH) {
        const int i = tid, o = u * HH + i;
        cz[o] = Wz[(size_t)i * (VV + HH) + v] + Wzb[i];
        const float r1 = Wr[(size_t)i * VV + v] + Wrb[i];
        r1s[o] = r1;
        sig0[o] = 1.f / (1.f + expf(-r1));
        ch[o] = Wh[(size_t)i * (VV + HH) + v] + Whb[i];
        float d = Wd12[(size_t)i * (VV + LATD) + v] + Wd12b[i];
        for (int k = 0; k < LATD; ++k)
            d += Wd12[(size_t)i * (VV + LATD) + VV + k] * latent[k];
        p = Ud[i] * fmaxf(d, 0.f);
    }
    p = wred_sum(p);
    if ((tid & 63) == 0) red[tid >> 6] = p;
    __syncthreads();
    if (tid == 0) {
        float s = 0.f;
        for (int w = 0; w < 8; ++w) s += red[w];
        dotd12[u] = s;
    }
}

// ---- WhSig0[u] = Wh_H @ sigma(r1[u]) ----
__global__ __launch_bounds__(512) void k_whsig0(
    const float* __restrict__ Wh, const float* __restrict__ sig0, float* __restrict__ out)
{
    const int u = blockIdx.x, tid = threadIdx.x, wave = tid >> 6, lane = tid & 63;
    __shared__ float sg[HH];
    if (tid < HH) sg[tid] = sig0[u * HH + tid];
    __syncthreads();
    for (int r = wave; r < HH; r += 8) {
        float acc = 0.f;
        for (int k = lane; k < HH; k += 64)
            acc += Wh[(size_t)r * (VV + HH) + VV + k] * sg[k];
        acc = wred_sum(acc);
        if (lane == 0) out[u * HH + r] = acc;
    }
}

// ---- per-step exclusion index + precomputed neighbor-count coefficient ----
__global__ void k_excl(const int* __restrict__ node_ids, const int* __restrict__ next_ids,
                       int* __restrict__ excl, float* __restrict__ ccpre)
{
    const int t = blockIdx.x;
    __shared__ int ex, cnt;
    if (threadIdx.x == 0) { ex = -1; cnt = 0; }
    __syncthreads();
    const int a = node_ids[t], b = next_ids[t];
    for (int tp = threadIdx.x; tp <= t; tp += blockDim.x) {
        if (tp < t && node_ids[tp] == b && next_ids[tp] == a) ex = tp;
        if (tp >= 1 && node_ids[tp] == a) atomicAdd(&cnt, 1);
    }
    __syncthreads();
    if (threadIdx.x == 0) {
        excl[t] = ex;
        ccpre[t] = 256.f - (float)cnt + (ex >= 0 ? 1.f : 0.f);
    }
}

// ---- copy stops/real_labels into d_out; zero the pred_stop region ----
__global__ void k_copy(const int* __restrict__ stops, const int* __restrict__ reall,
                       float* __restrict__ out)
{
    const int i = blockIdx.x * blockDim.x + threadIdx.x;
    if (i < LL) { out[i] = (float)stops[i]; out[LL + i] = 0.f; }
    if (i < NN) out[2 * LL + i] = (float)reall[i];
}

// ---- sequential scan: counted fixed-point dataflow, ~1 coherence RT/step ----
// Block b owns rows R_b. Column-partitioned first layer (Ur/Wz_H/Wd3): thread
// r adds its partial as u64 (count<<45 | fixed24 value) into monotone
// parity-double-buffered row accumulators. Consumers poll ONE word per row:
// count field == 32*n_uses <=> all producers landed; low field = exact
// cumulative sum (diff vs per-thread prev = this step's value). No drain,
// no flags, no central counter. sigma computed redundantly for all rows;
// Wh matvec row-partitioned with register-resident rows.
__global__ __launch_bounds__(TSEQ) void k_seq(
    const int* __restrict__ node_ids, const int* __restrict__ excl,
    const float* __restrict__ ccpre,
    const float* __restrict__ Ur, const float* __restrict__ Wz,
    const float* __restrict__ Wh, const float* __restrict__ Wd3,
    const float* __restrict__ Wd3b, const float* __restrict__ Ud,
    const float* __restrict__ Udb,
    const float* __restrict__ cz, const float* __restrict__ r1s,
    const float* __restrict__ ch, const float* __restrict__ WhSig0,
    const float* __restrict__ dotd12,
    float* __restrict__ SmL, float* __restrict__ WzSmL,
    float* __restrict__ Wd3SmL, float* __restrict__ WhRsL,
    float* __restrict__ NewHL, float* __restrict__ WzML, float* __restrict__ WhSvL,
    unsigned long long* __restrict__ bufUr, unsigned long long* __restrict__ bufWz,
    unsigned long long* __restrict__ bufWd3,
    float* __restrict__ pred_out)
{
    const int tid = threadIdx.x, bid = blockIdx.x;
    const int wave = tid >> 6, lane = tid & 63;
    const int kcnt = 14 + (bid < 2 ? 1 : 0);
    const int kbeg = 14 * bid + (bid < 2 ? bid : 2);

    float* mySm   = SmL    + (size_t)bid * NN * AST;
    float* myWzSm = WzSmL  + (size_t)bid * NN * AST;
    float* myWd3S = Wd3SmL + (size_t)bid * NN * AST;
    float* myWhRs = WhRsL  + (size_t)bid * NN * AST;
    float* myNewH = NewHL  + (size_t)bid * LL * AST;
    float* myWzM  = WzML   + (size_t)bid * LL * AST;
    float* myWhSv = WhSvL  + (size_t)bid * LL * AST;

    __shared__ float nh_s[KMAX];
    __shared__ float sig_full[512];

    // Column slices of Ur / Wz_H / Wd3: thread r holds row r's R_b columns
    float ur_c[KMAX], wz_c[KMAX], wd3_c[KMAX];
    for (int j = 0; j < KMAX; ++j) {
        const bool v = (tid < HH) && (j < kcnt);
        ur_c[j]  = v ? Ur[(size_t)tid * HH + kbeg + j] : 0.f;
        wz_c[j]  = v ? Wz[(size_t)tid * (VV + HH) + VV + kbeg + j] : 0.f;
        wd3_c[j] = v ? Wd3[(size_t)tid * HH + kbeg + j] : 0.f;
    }
    // Row slice of Wh_H (second matvec, row-partitioned fold)
    float wh_r[2][8];
    for (int it = 0; it < 2; ++it) {
        const int j = wave + 8 * it;
        const bool vj = j < kcnt;
        const int i = vj ? (kbeg + j) : 0;
        for (int e = 0; e < 8; ++e) {
            const int c = lane + 64 * e;
            wh_r[it][e] = (vj && c < HH) ? Wh[(size_t)i * (VV + HH) + VV + c] : 0.f;
        }
    }
    if (tid >= HH) sig_full[tid] = 0.f;   // zero pad once

    long long prevU[2] = {0, 0};   // cumulative fixed-point trackers
    long long prevZ[2] = {0, 0};
    long long prevD[2] = {0, 0};
    int nUse[2] = {0, 0};
    __syncthreads();

    for (int t = 1; t <= LL; ++t) {
        const int ap  = node_ids[t - 1];
        const int idx = excl[t - 1];
        // ---- A: new_h(t-1) own rows (all-local reads) ----
        float nh = 0.f;
        if (tid < kcnt) {
            const int r = kbeg + tid;
            const int o = ap * HH + r;
            const int oa = ap * AST + tid;
            float zarg = myWzSm[oa] + cz[o];
            float whv  = myWhRs[oa] + ch[o];
            float sv   = mySm[oa];
            if (idx >= 0) {
                const int oe = idx * AST + tid;
                zarg -= myWzM[oe]; whv -= myWhSv[oe]; sv -= myNewH[oe];
            }
            whv += ccpre[t - 1] * WhSig0[o];
            const float z = 1.f / (1.f + expf(-zarg));
            nh = (1.f - z) * sv + z * tanhf(whv);
            nh_s[tid] = nh;
            myNewH[(t - 1) * AST + tid] = nh;
        }
        if (t == LL) {
            // final pred_stop then exit (no ingestion)
            if (wave == 0) {
                float ps = 0.f;
                if (tid < kcnt) {
                    const int r = kbeg + tid;
                    ps = Ud[HH + r] * fmaxf(myWd3S[ap * AST + tid] + Wd3b[r], 0.f);
                }
                ps = wred_sum(ps);
                if (lane == 0) {
                    if (bid == 0) ps += dotd12[ap] + Udb[0];
                    aaddf(&pred_out[t - 1], ps);
                }
            }
            break;
        }
        const int a = node_ids[t];
        __syncthreads();       // nh_s visible

        const int p = t & 1;
        nUse[p] += 1;
        const long long tgtc = (long long)(32 * nUse[p]);
        // ---- fan-out: counted fixed-point adds (chain-critical, issue first) ----
        if (tid < HH) {
            float au = 0.f, az = 0.f, ad = 0.f;
            for (int j = 0; j < kcnt; ++j) {
                const float m = nh_s[j];
                au += ur_c[j]  * m;
                az += wz_c[j]  * m;
                ad += wd3_c[j] * m;
            }
            aadd64(&bufUr[p * 512 + tid],  packc(au));
            aadd64(&bufWz[p * 512 + tid],  packc(az));
            aadd64(&bufWd3[p * 512 + tid], packc(ad));
        }
        if (tid < kcnt) mySm[a * AST + tid] += nh;   // local fold
        // pred_stop(t-1): off the critical chain; fire-and-forget
        if (wave == 0) {
            float ps = 0.f;
            if (tid < kcnt) {
                const int r = kbeg + tid;
                ps = Ud[HH + r] * fmaxf(myWd3S[ap * AST + tid] + Wd3b[r], 0.f);
            }
            ps = wred_sum(ps);
            if (lane == 0) {
                if (bid == 0) ps += dotd12[ap] + Udb[0];
                aaddf(&pred_out[t - 1], ps);
            }
        }

        // ---- poll-gather: one u64 per row, completion embedded in value ----
        if (tid < HH) {
            const unsigned long long* pw = &bufUr[p * 512 + tid];
            long long x = aload64(pw);
            while (((x + CHALF) >> 45) != tgtc) { __builtin_amdgcn_s_sleep(0); x = aload64(pw); }
            const long long sf = x - (tgtc << 45);
            const long long d = sf - prevU[p]; prevU[p] = sf;
            const float urm = (float)d * (1.f / FIXS);
            sig_full[tid] = 1.f / (1.f + expf(-(urm + r1s[a * HH + tid])));
        } else if (tid < HH + KMAX) {
            const int j = tid - HH;
            if (j < kcnt) {
                const unsigned long long* pw = &bufWz[p * 512 + kbeg + j];
                long long x = aload64(pw);
                while (((x + CHALF) >> 45) != tgtc) { __builtin_amdgcn_s_sleep(0); x = aload64(pw); }
                const long long sf = x - (tgtc << 45);
                const long long d = sf - prevZ[p]; prevZ[p] = sf;
                const float wzm = (float)d * (1.f / FIXS);
                myWzM[(t - 1) * AST + j] = wzm;
                myWzSm[a * AST + j] += wzm;
            }
        } else if (tid < HH + 2 * KMAX) {
            const int j = tid - HH - KMAX;
            if (j < kcnt) {
                const unsigned long long* pw = &bufWd3[p * 512 + kbeg + j];
                long long x = aload64(pw);
                while (((x + CHALF) >> 45) != tgtc) { __builtin_amdgcn_s_sleep(0); x = aload64(pw); }
                const long long sf = x - (tgtc << 45);
                const long long d = sf - prevD[p]; prevD[p] = sf;
                myWd3S[a * AST + j] += (float)d * (1.f / FIXS);
            }
        }
        __syncthreads();   // sig_full complete

        // ---- Wh fold: own rows x full sigma (register matvec) ----
        for (int it = 0; it < 2; ++it) {
            const int j = wave + 8 * it;
            float acc = 0.f;
            #pragma unroll
            for (int e = 0; e < 8; ++e) acc += wh_r[it][e] * sig_full[lane + 64 * e];
            acc = wred_sum(acc);
            if (lane == 0 && j < kcnt) {
                myWhSv[(t - 1) * AST + j] = acc;
                myWhRs[a * AST + j] += acc;
            }
        }
        __syncthreads();   // folds complete before next A reads them
    }
}

// ---- labels: root (q=0, outer relu, no softmax) + 255 label steps (softmax) ----
__global__ __launch_bounds__(512) void k_label(
    const float* __restrict__ latent, const int* __restrict__ lsteps,
    const float* __restrict__ NewHL,
    const float* __restrict__ Wl, const float* __restrict__ Wlb,
    const float* __restrict__ Ul, const float* __restrict__ Ulb,
    float* __restrict__ out)
{
    const int q = blockIdx.x, tid = threadIdx.x, wave = tid >> 6, lane = tid & 63;
    __shared__ float inp[LATD + HH];
    __shared__ float t2[HH];
    __shared__ float lg[VV];
    __shared__ float red[8];
    if (tid < LATD) inp[tid] = latent[tid];
    if (q == 0) {
        if (tid < HH) inp[LATD + tid] = 0.f;
    } else {
        const int t = lsteps[q - 1];
        if (tid < HH) {
            const int b = (tid < 30) ? (tid / 15) : (2 + (tid - 30) / 14);
            const int j = (tid < 30) ? (tid % 15) : ((tid - 30) % 14);
            inp[LATD + tid] = NewHL[((size_t)b * LL + t) * AST + j];
        }
    }
    __syncthreads();
    for (int r = wave; r < HH; r += 8) {
        float acc = 0.f;
        for (int k = lane; k < LATD + HH; k += 64)
            acc += Wl[(size_t)r * (LATD + HH) + k] * inp[k];
        acc = wred_sum(acc);
        if (lane == 0) {
            const float v = acc + Wlb[r];
            t2[r] = (q == 0) ? v : fmaxf(v, 0.f);   // root: no inner relu
        }
    }
    __syncthreads();
    for (int r = wave; r < VV; r += 8) {
        float acc = 0.f;
        for (int k = lane; k < HH; k += 64) acc += Ul[(size_t)r * HH + k] * t2[k];
        acc = wred_sum(acc);
        if (lane == 0) lg[r] = acc + Ulb[r];
    }
    __syncthreads();
    float* outrow = out + 2 * LL + NN + (size_t)q * VV;
    if (q == 0) {   // root: relu, no softmax
        for (int i = tid; i < VV; i += 512) outrow[i] = fmaxf(lg[i], 0.f);
        return;
    }
    float mx = -1e30f;
    for (int i = tid; i < VV; i += 512) mx = fmaxf(mx, lg[i]);
    for (int off = 32; off; off >>= 1) mx = fmaxf(mx, __shfl_down(mx, off, 64));
    if (lane == 0) red[wave] = mx;
    __syncthreads();
    if (tid == 0) {
        float m = red[0];
        for (int w = 1; w < 8; ++w) m = fmaxf(m, red[w]);
        red[0] = m;
    }
    __syncthreads();
    const float M = red[0];
    float sum = 0.f;
    for (int i = tid; i < VV; i += 512) { const float e = expf(lg[i] - M); lg[i] = e; sum += e; }
    __syncthreads();
    sum = wred_sum(sum);
    if (lane == 0) red[wave] = sum;
    __syncthreads();
    if (tid == 0) {
        float s = 0.f;
        for (int w = 0; w < 8; ++w) s += red[w];
        red[0] = s;
    }
    __syncthreads();
    const float S = red[0];
    for (int i = tid; i < VV; i += 512) outrow[i] = lg[i] / S;
}

extern "C" void kernel_launch(void* const* d_in, const int* in_sizes, int n_in,
                              void* d_out, int out_size, void* d_ws, size_t ws_size,
                              hipStream_t stream)
{
    const float* latent = (const float*)d_in[0];
    const float* nodef  = (const float*)d_in[1];
    const int* node_ids = (const int*)d_in[2];
    const int* next_ids = (const int*)d_in[3];
    const int* stops    = (const int*)d_in[4];
    const int* lsteps   = (const int*)d_in[5];
    const int* reall    = (const int*)d_in[6];
    const float* Wz   = (const float*)d_in[7];
    const float* Wzb  = (const float*)d_in[8];
    const float* Urw  = (const float*)d_in[9];
    const float* Wr   = (const float*)d_in[10];
    const float* Wrb  = (const float*)d_in[11];
    const float* Wh   = (const float*)d_in[12];
    const float* Whb  = (const float*)d_in[13];
    const float* Wd12 = (const float*)d_in[14];
    const float* Wd12b= (const float*)d_in[15];
    const float* Wd3  = (const float*)d_in[16];
    const float* Wd3b = (const float*)d_in[17];
    const float* Ud   = (const float*)d_in[18];
    const float* Udb  = (const float*)d_in[19];
    const float* Wl   = (const float*)d_in[20];
    const float* Wlb  = (const float*)d_in[21];
    const float* Ul   = (const float*)d_in[22];
    const float* Ulb  = (const float*)d_in[23];
    (void)in_sizes; (void)n_in; (void)out_size; (void)ws_size;
    float* out = (float*)d_out;
    float* W = (float*)d_ws;

    size_t o = 0;
    float* SmL    = W + o; o += (size_t)GSEQ * NN * AST;
    float* WzSmL  = W + o; o += (size_t)GSEQ * NN * AST;
    float* Wd3SmL = W + o; o += (size_t)GSEQ * NN * AST;
    float* WhRsL  = W + o; o += (size_t)GSEQ * NN * AST;
    unsigned long long* bufUr  = (unsigned long long*)(W + o); o += 2 * 2 * 512;
    unsigned long long* bufWz  = (unsigned long long*)(W + o); o += 2 * 2 * 512;
    unsigned long long* bufWd3 = (unsigned long long*)(W + o); o += 2 * 2 * 512;
    const size_t zero_floats = o;           // everything above must start at 0
    int*   vid    = (int*)(W + o); o += NN;
    int*   excl   = (int*)(W + o); o += LL + 1;
    float* ccpre  = W + o; o += LL + 1;
    float* cz     = W + o; o += NN * HH;
    float* r1s    = W + o; o += NN * HH;
    float* sig0   = W + o; o += NN * HH;
    float* ch     = W + o; o += NN * HH;
    float* WhSig0 = W + o; o += NN * HH;
    float* dotd12 = W + o; o += NN;
    float* NewHL  = W + o; o += (size_t)GSEQ * LL * AST;
    float* WzML   = W + o; o += (size_t)GSEQ * LL * AST;
    float* WhSvL  = W + o; o += (size_t)GSEQ * LL * AST;

    hipMemsetAsync(W, 0, zero_floats * sizeof(float), stream);
    k_vid   <<<NN, 256, 0, stream>>>(nodef, vid);
    k_consts<<<NN, 512, 0, stream>>>(vid, latent, Wz, Wzb, Wr, Wrb, Wh, Whb,
                                     Wd12, Wd12b, Ud, cz, r1s, sig0, ch, dotd12);
    k_whsig0<<<NN, 512, 0, stream>>>(Wh, sig0, WhSig0);
    k_excl  <<<LL, 256, 0, stream>>>(node_ids, next_ids, excl, ccpre);
    k_copy  <<<2, 256, 0, stream>>>(stops, reall, out);
    k_seq   <<<GSEQ, TSEQ, 0, stream>>>(node_ids, excl, ccpre, Urw, Wz, Wh, Wd3, Wd3b,
                                        Ud, Udb, cz, r1s, ch, WhSig0, dotd12,
                                        SmL, WzSmL, Wd3SmL, WhRsL,
                                        NewHL, WzML, WhSvL,
                                        bufUr, bufWz, bufWd3,
                                        out + LL);
    k_label <<<NN, 512, 0, stream>>>(latent, lsteps, NewHL, Wl, Wlb, Ul, Ulb, out);
}